// Round 9
// baseline (93.525 us; speedup 1.0000x reference)
//
#include <hip/hip_runtime.h>
#include <math.h>

// RoI max pooling (JAX reference): features [1,C,H,W] fp32, rois [R,4] int32
// (x1,y1,x2,y2 inclusive), P=7. Boundaries b[i]=trunc(x1 + fl32(rw/7)*i),
// each op rounded separately (no FMA). Setup guarantees 8 <= rw,rh <= 64.
//
// R9: persistent blocks. R6-R8 occupancy pinned at ~11 waves/CU regardless of
// LDS/block shape; 16384 wg / 190K cy ~= 12 cy/wg = dispatch-rate equilibrium
// -> the per-task workgroup-dispatch cost was the cap. Now grid = 4096
// one-wave blocks (= exactly 16 resident wg/CU by LDS: 16 x 8KB = 131KB), and
// each block runs 4 tasks, one per pass: fixed (roi,half) = bid>>3, channel
// group = (pass<<3) | (bid&7). XCD L2 window stays exactly one group; per-ROI
// prologue computed once for all 4 tasks. Wave body = R8 (imm-offset full-4
// row loads, slot clamp, [k][ph][72] staging, inline bin-edge recompute).

#define POOL_P 7

__device__ __forceinline__ float4 max4(float4 a, float4 b) {
  return make_float4(fmaxf(a.x, b.x), fmaxf(a.y, b.y),
                     fmaxf(a.z, b.z), fmaxf(a.w, b.w));
}

__global__ __launch_bounds__(64) void roipool_kernel(
    const float* __restrict__ feat, const int* __restrict__ rois,
    float* __restrict__ out, int C, int H, int W, int R) {
  const int xcd   = blockIdx.x & 7;   // bid%8 = XCD (verified R5: FETCH 285->65MB)
  const int bslot = blockIdx.x >> 3;  // 0..511 within XCD
  const int r     = bslot >> 1;       // roi (same for all passes)
  const int half  = bslot & 1;        // which 4-channel half of the 8-ch group

  const int lane = threadIdx.x;       // one wave per block
  const int k  = lane >> 4;           // channel within wave (0..3)
  const int li = lane & 15;           // float4 slot in 64-col window

  // ---- per-ROI prologue: once for all 4 tasks ----
  const int4 roi = *reinterpret_cast<const int4*>(rois + 4 * r);
  const int x1 = roi.x, y1 = roi.y;
  const int rw = max(roi.z - x1 + 1, 1);
  const int rh = max(roi.w - y1 + 1, 1);
  const int x2 = x1 + rw - 1;

  // bit-exact fp32 bin math: div, mul, add each rounded; trunc==floor (>=0)
  const float sx = __fdiv_rn((float)rw, (float)POOL_P);
  const float sy = __fdiv_rn((float)rh, (float)POOL_P);
  const float x1f = (float)x1, y1f = (float)y1;

  const int xa = x1 & ~3;              // 16B-aligned window start
  const bool tailc = (x2 >= xa + 64);  // cols xa+64..66 (x2 <= xa+66 <= 334)
  const int lslot = min((x2 - xa) >> 2, 15);
  const int lic = min(li, lslot);      // surplus lanes dup last needed slot

  // row-bin boundaries don't depend on channel: hoist h0/hend per ph? They
  // are recomputed per ph below (cheap, 2 VALU) to avoid an indexed array.

  const size_t HW = (size_t)H * W;
  const int W4 = W >> 2;               // 84 float4 per row

  __shared__ float stg[4][POOL_P][72]; // [k][ph][col] — ph stride 72 = 8 mod 32

  const float NEG = -__builtin_inff();

  for (int pass = 0; pass < 4; ++pass) {
    const int cg8 = (pass << 3) | xcd;           // 8-channel group for this pass
    const int c0  = (cg8 << 3) + (half << 2);    // wave's first channel
    const float* fck = feat + (size_t)(c0 + k) * HW;
    const float4* pmb = reinterpret_cast<const float4*>(fck + xa) + lic;
    const float* pt  = fck + xa + 64;

    // ---- phase 1: stream all 7 row-bins' loads ----
#pragma unroll
    for (int ph = 0; ph < POOL_P; ++ph) {
      const int h0   = (int)__fadd_rn(y1f, __fmul_rn(sy, (float)ph));
      const int hend = (int)__fadd_rn(y1f, __fmul_rn(sy, (float)(ph + 1)));
      const int cnt = hend - h0;         // >= 1 (rh >= 8)
      const float4* p4 = pmb + (size_t)h0 * W4;
      float4 m = make_float4(NEG, NEG, NEG, NEG);
      for (int it = cnt >> 2; it > 0; --it) {
        float4 v0 = p4[0];               // imm offsets 0/1344/2688/4032 B
        float4 v1 = p4[84];
        float4 v2 = p4[168];
        float4 v3 = p4[252];
        m = max4(m, max4(max4(v0, v1), max4(v2, v3)));
        p4 += 336;                       // 4 rows
      }
      const int rem = cnt & 3;
      if (rem) {                         // 1..3 rows, clamped dups (L1 hits)
        const int o1 = (rem > 1) ? 84 : 0;
        const int o2 = (rem > 2) ? 168 : o1;
        float4 v0 = p4[0];
        float4 v1 = p4[o1];
        float4 v2 = p4[o2];
        m = max4(m, max4(v0, max4(v1, v2)));
      }
      // slots > lslot hold dups; never read in phase 2
      *reinterpret_cast<float4*>(&stg[k][ph][li << 2]) = m;
    }

    // ---- rare tail pass (~4% of ROIs): cols xa+64..xa+66 ----
    if (tailc && li == 0) {
#pragma unroll
      for (int ph = 0; ph < POOL_P; ++ph) {
        const int h0   = (int)__fadd_rn(y1f, __fmul_rn(sy, (float)ph));
        const int hend = (int)__fadd_rn(y1f, __fmul_rn(sy, (float)(ph + 1)));
        float4 tm = make_float4(NEG, NEG, NEG, NEG);
        for (int h = h0; h < hend; ++h)
          tm = max4(tm, *reinterpret_cast<const float4*>(pt + (size_t)h * W));
        *reinterpret_cast<float4*>(&stg[k][ph][64]) = tm;
      }
    }

    // ---- phase 2: all 64 lanes reduce column bins, write out ----
    // wave-private LDS: program order + lgkmcnt ordering, no barrier needed;
    // next pass's phase-1 overwrite of stg is also same-wave in-order (WAR safe)
    const size_t ob = ((size_t)r * C + c0) * (POOL_P * POOL_P);
#pragma unroll
    for (int i = lane; i < 4 * POOL_P * POOL_P; i += 64) {
      const int k2 = i / (POOL_P * POOL_P);
      const int j  = i - k2 * (POOL_P * POOL_P);
      const int ph = j / POOL_P;
      const int pw = j - ph * POOL_P;
      const int w0 = (int)__fadd_rn(x1f, __fmul_rn(sx, (float)pw)) - xa;
      const int w1 = (int)__fadd_rn(x1f, __fmul_rn(sx, (float)(pw + 1))) - xa;
      const float* sq = &stg[k2][ph][0];
      float m = NEG;
      for (int w = w0; w < w1; ++w) m = fmaxf(m, sq[w]);
      out[ob + i] = m;   // contiguous across lanes
    }
  }
}

extern "C" void kernel_launch(void* const* d_in, const int* in_sizes, int n_in,
                              void* d_out, int out_size, void* d_ws, size_t ws_size,
                              hipStream_t stream) {
  const float* feat = (const float*)d_in[0];
  const int*   rois = (const int*)d_in[1];
  float*       out  = (float*)d_out;

  const int C = 256, H = 336, W = 336;  // fixed by setup_inputs()
  const int R = in_sizes[1] / 4;        // 256 rois

  // persistent: 4096 blocks = 512/XCD = 16 wg/CU resident; each does 4 tasks
  dim3 grid(4096), block(64);
  roipool_kernel<<<grid, block, 0, stream>>>(feat, rois, out, C, H, W, R);
}

// Round 10
// 51.195 us; speedup vs baseline: 1.8268x; 1.8268x over previous
//
#include <hip/hip_runtime.h>
#include <math.h>

// RoI max pooling (JAX reference): features [1,C,H,W] fp32, rois [R,4] int32
// (x1,y1,x2,y2 inclusive), P=7. Boundaries b[i]=trunc(x1 + fl32(rw/7)*i),
// each op rounded separately (no FMA). Setup guarantees 8 <= rw,rh <= 64.
//
// R10: back to R8's grid (persistent R9 regressed: no refill -> tail idle).
// Warm replays fetch ~0 HBM yet run ~79us => L2-resident, in-wave-latency
// bound. Fix MLP: (a) phase 1 straight-line: per bin always 8 row loads with
// clamped uniform offsets min(j,e)*84 (dup rows idempotent under max, hit
// just-fetched lines); rare rh>=57 tail loop. Compiler can hold 8+ loads in
// flight and overlap bins. (b) phase 2: 4 unconditional ds_read_b128 +
// predicated max over 16 elems (select-before-max => NaN-garbage safe),
// latency-flat instead of ~10 dependent ds_read->fmax pairs per output.
// stg [4][7][80] so vector reads stay in-array. launch_bounds(64,4) caps
// VGPR at 128 (16 waves/CU).

#define POOL_P 7

__device__ __forceinline__ float4 max4(float4 a, float4 b) {
  return make_float4(fmaxf(a.x, b.x), fmaxf(a.y, b.y),
                     fmaxf(a.z, b.z), fmaxf(a.w, b.w));
}

__global__ __launch_bounds__(64, 4) void roipool_kernel(
    const float* __restrict__ feat, const int* __restrict__ rois,
    float* __restrict__ out, int C, int H, int W, int R) {
  // XCD-aware decode: bid%8 = XCD; XCD x runs channel-group {x, x+8, ...}
  // over all R rois x 2 halves (one "pass") before its next group.
  const int x  = blockIdx.x & 7;
  const int s  = blockIdx.x >> 3;
  const int pass = s / (2 * R);
  const int t    = s - pass * 2 * R;
  const int r    = t >> 1;
  const int half = t & 1;
  const int cg8  = (pass << 3) | x;        // 8-channel group

  const int lane = threadIdx.x;            // one wave per block
  const int k  = lane >> 4;                // channel within wave (0..3)
  const int li = lane & 15;                // float4 slot in 64-col window
  const int c0 = (cg8 << 3) + (half << 2); // wave's first channel

  const int4 roi = *reinterpret_cast<const int4*>(rois + 4 * r);
  const int x1 = roi.x, y1 = roi.y;
  const int rw = max(roi.z - x1 + 1, 1);
  const int rh = max(roi.w - y1 + 1, 1);
  const int x2 = x1 + rw - 1;

  // bit-exact fp32 bin math: div, mul, add each rounded; trunc==floor (>=0)
  const float sx = __fdiv_rn((float)rw, (float)POOL_P);
  const float sy = __fdiv_rn((float)rh, (float)POOL_P);
  const float x1f = (float)x1, y1f = (float)y1;

  const int xa = x1 & ~3;              // 16B-aligned window start
  const bool tailc = (x2 >= xa + 64);  // cols xa+64..66 (x2 <= xa+66 <= 334)

  // slot clamp: only load needed float4 slots; surplus lanes dup last slot
  const int lslot = min((x2 - xa) >> 2, 15);
  const int lic = min(li, lslot);

  const size_t HW = (size_t)H * W;
  const int W4 = W >> 2;               // 84 float4 per row
  const float* fck = feat + (size_t)(c0 + k) * HW;
  const float4* pmb = reinterpret_cast<const float4*>(fck + xa) + lic;
  const float* pt  = fck + xa + 64;

  __shared__ float stg[4][POOL_P][80]; // [k][ph][col]; 80: vec-read headroom

  const float NEG = -__builtin_inff();

  // ---- phase 1: straight-line 8 clamped row loads per bin ----
#pragma unroll
  for (int ph = 0; ph < POOL_P; ++ph) {
    const int h0   = (int)__fadd_rn(y1f, __fmul_rn(sy, (float)ph));
    const int hend = (int)__fadd_rn(y1f, __fmul_rn(sy, (float)(ph + 1)));
    const int cnt = hend - h0;           // 1..10
    const int e84 = (cnt - 1) * 84;      // wave-uniform clamp (float4 units)
    const float4* q = pmb + (size_t)h0 * W4;
    float4 v0 = q[0];
    float4 v1 = q[min(84,  e84)];
    float4 v2 = q[min(168, e84)];
    float4 v3 = q[min(252, e84)];
    float4 v4 = q[min(336, e84)];
    float4 v5 = q[min(420, e84)];
    float4 v6 = q[min(504, e84)];
    float4 v7 = q[min(588, e84)];
    float4 m = max4(max4(max4(v0, v1), max4(v2, v3)),
                    max4(max4(v4, v5), max4(v6, v7)));
    if (cnt > 8) {                       // rare: rh >= 57, <= 2 extra rows
      const float4* qq = q + 8 * 84;
      for (int h = h0 + 8; h < hend; ++h) { m = max4(m, qq[0]); qq += 84; }
    }
    // slots > lslot hold dups; never read in phase 2
    *reinterpret_cast<float4*>(&stg[k][ph][li << 2]) = m;
  }

  // ---- rare tail pass (~4% of ROIs): cols xa+64..xa+66 ----
  if (tailc && li == 0) {
#pragma unroll
    for (int ph = 0; ph < POOL_P; ++ph) {
      const int h0   = (int)__fadd_rn(y1f, __fmul_rn(sy, (float)ph));
      const int hend = (int)__fadd_rn(y1f, __fmul_rn(sy, (float)(ph + 1)));
      float4 tm = make_float4(NEG, NEG, NEG, NEG);
      for (int h = h0; h < hend; ++h)
        tm = max4(tm, *reinterpret_cast<const float4*>(pt + (size_t)h * W));
      *reinterpret_cast<float4*>(&stg[k][ph][64]) = tm;
    }
  }

  // ---- phase 2: vectorized column-bin reduce, write out directly ----
  // wave-private LDS: program order + lgkmcnt ordering, no barrier needed
  const size_t ob = ((size_t)r * C + c0) * (POOL_P * POOL_P);
#pragma unroll
  for (int i = lane; i < 4 * POOL_P * POOL_P; i += 64) {
    const int k2 = i / (POOL_P * POOL_P);
    const int j  = i - k2 * (POOL_P * POOL_P);
    const int ph = j / POOL_P;
    const int pw = j - ph * POOL_P;
    // bin edges recomputed inline (bit-exact; no runtime-indexed array)
    const int w0 = (int)__fadd_rn(x1f, __fmul_rn(sx, (float)pw)) - xa;
    const int w1 = (int)__fadd_rn(x1f, __fmul_rn(sx, (float)(pw + 1))) - xa;
    const int a0 = w0 & ~3;              // 16B-aligned; w1-a0 <= 13 < 16
    const float* sq = &stg[k2][ph][a0];
    float4 t0 = *reinterpret_cast<const float4*>(sq);
    float4 t1 = *reinterpret_cast<const float4*>(sq + 4);
    float4 t2 = *reinterpret_cast<const float4*>(sq + 8);
    float4 t3 = *reinterpret_cast<const float4*>(sq + 12);
    const int lo = w0 - a0, hi = w1 - a0;
    float e[16] = {t0.x, t0.y, t0.z, t0.w, t1.x, t1.y, t1.z, t1.w,
                   t2.x, t2.y, t2.z, t2.w, t3.x, t3.y, t3.z, t3.w};
    float m = NEG;
#pragma unroll
    for (int jj = 0; jj < 16; ++jj) {    // select-before-max: garbage/NaN safe
      const float v = (jj >= lo && jj < hi) ? e[jj] : NEG;
      m = fmaxf(m, v);
    }
    out[ob + i] = m;                     // contiguous across lanes
  }
}

extern "C" void kernel_launch(void* const* d_in, const int* in_sizes, int n_in,
                              void* d_out, int out_size, void* d_ws, size_t ws_size,
                              hipStream_t stream) {
  const float* feat = (const float*)d_in[0];
  const int*   rois = (const int*)d_in[1];
  float*       out  = (float*)d_out;

  const int C = 256, H = 336, W = 336;  // fixed by setup_inputs()
  const int R = in_sizes[1] / 4;        // 256 rois

  const int n_cg8 = C / 8;              // 32 channel groups
  dim3 grid(n_cg8 * R * 2), block(64);  // R8 grid: 1 wave/block, 2 halves
  roipool_kernel<<<grid, block, 0, stream>>>(feat, rois, out, C, H, W, R);
}

// Round 11
// 51.013 us; speedup vs baseline: 1.8334x; 1.0036x over previous
//
#include <hip/hip_runtime.h>
#include <math.h>

// RoI max pooling (JAX reference): features [1,C,H,W] fp32, rois [R,4] int32
// (x1,y1,x2,y2 inclusive), P=7. Boundaries b[i]=trunc(x1 + fl32(rw/7)*i),
// each op rounded separately (no FMA). Setup guarantees 8 <= rw,rh <= 64.
//
// R11: request-stream diet (R6-R10 showed all pipes <35% busy, warm runs
// L3-fed => bound by vmem instr / line-touch service in the TA/L1 path).
// (a) exec-mask lanes li > lslot for all of phase 1: no dup 16B requests
//     (~35% lane-bytes cut). Unwritten stg slots are stale but phase 2
//     select-before-max never consumes them.
// (b) row-count dispatch: 4 clamped loads + 4 more if cnt>4 + rare loop
//     (E[loads/bin] 8 -> ~6.2).
// (c) chained bin boundaries: hend(ph) = h0(ph+1), half the bin VALU.
// Grid/layout = R8: 1-wave blocks, XCD pass decode, stg[4][7][80].

#define POOL_P 7

__device__ __forceinline__ float4 max4(float4 a, float4 b) {
  return make_float4(fmaxf(a.x, b.x), fmaxf(a.y, b.y),
                     fmaxf(a.z, b.z), fmaxf(a.w, b.w));
}

__global__ __launch_bounds__(64, 4) void roipool_kernel(
    const float* __restrict__ feat, const int* __restrict__ rois,
    float* __restrict__ out, int C, int H, int W, int R) {
  // XCD-aware decode: bid%8 = XCD; XCD x runs channel-group {x, x+8, ...}
  // over all R rois x 2 halves (one "pass") before its next group.
  const int x  = blockIdx.x & 7;
  const int s  = blockIdx.x >> 3;
  const int pass = s / (2 * R);
  const int t    = s - pass * 2 * R;
  const int r    = t >> 1;
  const int half = t & 1;
  const int cg8  = (pass << 3) | x;        // 8-channel group

  const int lane = threadIdx.x;            // one wave per block
  const int k  = lane >> 4;                // channel within wave (0..3)
  const int li = lane & 15;                // float4 slot in 64-col window
  const int c0 = (cg8 << 3) + (half << 2); // wave's first channel

  const int4 roi = *reinterpret_cast<const int4*>(rois + 4 * r);
  const int x1 = roi.x, y1 = roi.y;
  const int rw = max(roi.z - x1 + 1, 1);
  const int rh = max(roi.w - y1 + 1, 1);
  const int x2 = x1 + rw - 1;

  // bit-exact fp32 bin math: div, mul, add each rounded; trunc==floor (>=0)
  const float sx = __fdiv_rn((float)rw, (float)POOL_P);
  const float sy = __fdiv_rn((float)rh, (float)POOL_P);
  const float x1f = (float)x1, y1f = (float)y1;

  const int xa = x1 & ~3;              // 16B-aligned window start
  const bool tailc = (x2 >= xa + 64);  // cols xa+64..66 (x2 <= xa+66 <= 334)
  const int lslot = min((x2 - xa) >> 2, 15);  // last needed float4 slot

  const size_t HW = (size_t)H * W;
  const int W4 = W >> 2;               // 84 float4 per row
  const float* fck = feat + (size_t)(c0 + k) * HW;
  const float4* pmb = reinterpret_cast<const float4*>(fck + xa) + li;
  const float* pt  = fck + xa + 64;

  __shared__ float stg[4][POOL_P][80]; // [k][ph][col]; 80: vec-read headroom

  const float NEG = -__builtin_inff();

  // ---- phase 1: masked lanes, row-count-dispatched clamped loads ----
  if (li <= lslot) {                   // one divergence mask for all loads
    int hprev = y1;                    // b[0] = trunc(y1f) = y1 exactly
#pragma unroll
    for (int ph = 0; ph < POOL_P; ++ph) {
      const int hend = (int)__fadd_rn(y1f, __fmul_rn(sy, (float)(ph + 1)));
      const int cnt = hend - hprev;    // 1..10 (rh <= 64)
      const int e84 = (cnt - 1) * 84;  // wave-uniform row clamp (float4 units)
      const float4* q = pmb + (size_t)hprev * W4;
      hprev = hend;
      float4 m = q[0];
      m = max4(m, q[min(84,  e84)]);   // dups when cnt<4: same lines, L1 hits
      m = max4(m, q[min(168, e84)]);
      m = max4(m, q[min(252, e84)]);
      if (cnt > 4) {
        float4 a = q[336];             // cnt>=5 => e84>=336: unclamped
        float4 b = q[min(420, e84)];
        float4 c = q[min(504, e84)];
        float4 d = q[min(588, e84)];
        m = max4(m, max4(max4(a, b), max4(c, d)));
      }
      if (cnt > 8) {                   // rare: rh >= 57
        const float4* qq = q + 672;
        for (int h = 8; h < cnt; ++h) { m = max4(m, qq[0]); qq += 84; }
      }
      *reinterpret_cast<float4*>(&stg[k][ph][li << 2]) = m;
    }
  }

  // ---- rare tail pass (~4% of ROIs): cols xa+64..xa+66 ----
  if (tailc && li == 0) {
    int hprev = y1;
#pragma unroll
    for (int ph = 0; ph < POOL_P; ++ph) {
      const int hend = (int)__fadd_rn(y1f, __fmul_rn(sy, (float)(ph + 1)));
      float4 tm = make_float4(NEG, NEG, NEG, NEG);
      for (int h = hprev; h < hend; ++h)
        tm = max4(tm, *reinterpret_cast<const float4*>(pt + (size_t)h * W));
      hprev = hend;
      *reinterpret_cast<float4*>(&stg[k][ph][64]) = tm;
    }
  }

  // ---- phase 2: vectorized column-bin reduce, write out directly ----
  // wave-private LDS: program order + lgkmcnt ordering, no barrier needed
  const size_t ob = ((size_t)r * C + c0) * (POOL_P * POOL_P);
#pragma unroll
  for (int i = lane; i < 4 * POOL_P * POOL_P; i += 64) {
    const int k2 = i / (POOL_P * POOL_P);
    const int j  = i - k2 * (POOL_P * POOL_P);
    const int ph = j / POOL_P;
    const int pw = j - ph * POOL_P;
    // bin edges recomputed inline (bit-exact; no runtime-indexed array)
    const int w0 = (int)__fadd_rn(x1f, __fmul_rn(sx, (float)pw)) - xa;
    const int w1 = (int)__fadd_rn(x1f, __fmul_rn(sx, (float)(pw + 1))) - xa;
    const int a0 = w0 & ~3;              // 16B-aligned; w1-a0 <= 13 < 16
    const float* sq = &stg[k2][ph][a0];
    float4 t0 = *reinterpret_cast<const float4*>(sq);
    float4 t1 = *reinterpret_cast<const float4*>(sq + 4);
    float4 t2 = *reinterpret_cast<const float4*>(sq + 8);
    float4 t3 = *reinterpret_cast<const float4*>(sq + 12);
    const int lo = w0 - a0, hi = w1 - a0;
    float e[16] = {t0.x, t0.y, t0.z, t0.w, t1.x, t1.y, t1.z, t1.w,
                   t2.x, t2.y, t2.z, t2.w, t3.x, t3.y, t3.z, t3.w};
    float m = NEG;
#pragma unroll
    for (int jj = 0; jj < 16; ++jj) {    // select-before-max: stale-slot safe
      const float v = (jj >= lo && jj < hi) ? e[jj] : NEG;
      m = fmaxf(m, v);
    }
    out[ob + i] = m;                     // contiguous across lanes
  }
}

extern "C" void kernel_launch(void* const* d_in, const int* in_sizes, int n_in,
                              void* d_out, int out_size, void* d_ws, size_t ws_size,
                              hipStream_t stream) {
  const float* feat = (const float*)d_in[0];
  const int*   rois = (const int*)d_in[1];
  float*       out  = (float*)d_out;

  const int C = 256, H = 336, W = 336;  // fixed by setup_inputs()
  const int R = in_sizes[1] / 4;        // 256 rois

  const int n_cg8 = C / 8;              // 32 channel groups
  dim3 grid(n_cg8 * R * 2), block(64);  // 1 wave/block, 2 halves per group
  roipool_kernel<<<grid, block, 0, stream>>>(feat, rois, out, C, H, W, R);
}